// Round 8
// baseline (409.153 us; speedup 1.0000x reference)
//
#include <hip/hip_runtime.h>
#include <stdint.h>

#define SQL 2048
#define HID 4096
#define NHEADS 32
#define HDSZ 128
#define QKVD 4608
#define QDIM 4096

typedef unsigned short u16;
typedef __attribute__((ext_vector_type(8))) short short8;
typedef __attribute__((ext_vector_type(4))) float f32x4;

#define AS1(p) ((__attribute__((address_space(1))) void*)(p))
#define AS3(p) ((__attribute__((address_space(3))) void*)(p))

__device__ __forceinline__ float bf2f(u16 u) {
  return __uint_as_float(((uint32_t)u) << 16);
}
__device__ __forceinline__ u16 f2bf(float f) {
  uint32_t x = __float_as_uint(f);
  x += 0x7fffu + ((x >> 16) & 1u);
  return (u16)(x >> 16);
}

// ---------- fp32 -> bf16 convert, 8 elems/thread ----------
__global__ void k_cvt(const float* __restrict__ in, u16* __restrict__ out, int n8) {
  int i = blockIdx.x * blockDim.x + threadIdx.x;
  int stride = gridDim.x * blockDim.x;
  for (; i < n8; i += stride) {
    const float4* p = reinterpret_cast<const float4*>(in) + (size_t)i * 2;
    float4 a = p[0], b = p[1];
    short8 o;
    o[0] = (short)f2bf(a.x); o[1] = (short)f2bf(a.y);
    o[2] = (short)f2bf(a.z); o[3] = (short)f2bf(a.w);
    o[4] = (short)f2bf(b.x); o[5] = (short)f2bf(b.y);
    o[6] = (short)f2bf(b.z); o[7] = (short)f2bf(b.w);
    reinterpret_cast<short8*>(out)[i] = o;
  }
}

// ---------- GEMM C[M][N] = A[M][K] * B[N][K]^T, bf16 MFMA ----------
// MODE 0: qkv epilogue (bias + scatter to q/k/vt).  MODE 1: fp32 C store.
template<int MODE>
__global__ __launch_bounds__(256, 2)
void k_gemm(const u16* __restrict__ A, const u16* __restrict__ B,
            const float* __restrict__ bias,
            u16* __restrict__ qbuf, u16* __restrict__ kbuf, u16* __restrict__ vtbuf,
            float* __restrict__ outf)
{
  __shared__ __align__(16) u16 ldsA[128 * 64];
  __shared__ __align__(16) u16 ldsB[128 * 64];
  const int tid = threadIdx.x;
  const int wid = tid >> 6, lane = tid & 63;
  const int l15 = lane & 15, lg = lane >> 4;
  const int m0 = blockIdx.y * 128, n0 = blockIdx.x * 128;
  const int wr = wid >> 1, wc = wid & 1;

  f32x4 acc[4][4] = {};

  const int srow = lane >> 3;                      // row within 8-row segment
  const int skb  = (((lane & 7) ^ srow) << 4);     // pre-swizzled source byte
  const size_t rowbytes = (size_t)HID * 2;

  for (int t = 0; t < HID / 64; ++t) {
    __syncthreads();
    const char* Ab = (const char*)A + (size_t)m0 * rowbytes + (size_t)t * 128;
    const char* Bb = (const char*)B + (size_t)n0 * rowbytes + (size_t)t * 128;
#pragma unroll
    for (int i = 0; i < 4; ++i) {
      int seg = i * 4 + wid;
      int row = seg * 8 + srow;
      __builtin_amdgcn_global_load_lds(AS1(Ab + (size_t)row * rowbytes + skb),
                                       AS3(ldsA + seg * 512), 16, 0, 0);
      __builtin_amdgcn_global_load_lds(AS1(Bb + (size_t)row * rowbytes + skb),
                                       AS3(ldsB + seg * 512), 16, 0, 0);
    }
    __syncthreads();
#pragma unroll
    for (int kc = 0; kc < 2; ++kc) {
      short8 af[4], bfr[4];
#pragma unroll
      for (int mi = 0; mi < 4; ++mi) {
        int row = wr * 64 + mi * 16 + l15;
        int kb = (kc * 64 + lg * 16) ^ ((row & 7) << 4);
        af[mi] = *reinterpret_cast<const short8*>((const char*)ldsA + row * 128 + kb);
      }
#pragma unroll
      for (int ni = 0; ni < 4; ++ni) {
        int row = wc * 64 + ni * 16 + l15;
        int kb = (kc * 64 + lg * 16) ^ ((row & 7) << 4);
        bfr[ni] = *reinterpret_cast<const short8*>((const char*)ldsB + row * 128 + kb);
      }
#pragma unroll
      for (int mi = 0; mi < 4; ++mi)
#pragma unroll
        for (int ni = 0; ni < 4; ++ni)
          acc[mi][ni] = __builtin_amdgcn_mfma_f32_16x16x32_bf16(af[mi], bfr[ni], acc[mi][ni], 0, 0, 0);
    }
  }

#pragma unroll
  for (int mi = 0; mi < 4; ++mi) {
#pragma unroll
    for (int ni = 0; ni < 4; ++ni) {
      int row0 = m0 + wr * 64 + mi * 16 + lg * 4;
      int col  = n0 + wc * 64 + ni * 16 + l15;
      if (MODE == 0) {
        float bv = bias[col];
#pragma unroll
        for (int j = 0; j < 4; ++j) {
          float v = acc[mi][ni][j] + bv;
          u16 hb = f2bf(v);
          int r = row0 + j;
          if (col < QDIM) {
            int hh = col >> 7, d = col & 127;
            qbuf[((size_t)hh * SQL + r) * HDSZ + d] = hb;
          } else if (col < QDIM + 256) {
            int c2 = col - QDIM; int g = c2 >> 7, d = c2 & 127;
            kbuf[((size_t)g * SQL + r) * HDSZ + d] = hb;
          } else {
            int c2 = col - QDIM - 256; int g = c2 >> 7, d = c2 & 127;
            vtbuf[((size_t)g * HDSZ + d) * SQL + r] = hb;   // V stored transposed
          }
        }
      } else {
#pragma unroll
        for (int j = 0; j < 4; ++j)
          outf[(size_t)(row0 + j) * QDIM + col] = acc[mi][ni][j];
      }
    }
  }
}

// ---------- RoPE (interleaved pairs, first 64 dims), in place on q and k ----------
__global__ void k_rope(u16* __restrict__ qbuf, u16* __restrict__ kbuf,
                       const float* __restrict__ rope) {
  int idx = blockIdx.x * blockDim.x + threadIdx.x;
  if (idx >= SQL * 34 * 32) return;
  int p = idx & 31;
  int hh = (idx >> 5) % 34;
  int s = idx / (34 * 32);
  float c  = rope[s * 64 + p * 2 + 0];
  float sn = rope[s * 64 + p * 2 + 1];
  u16* base = (hh < 32) ? (qbuf + ((size_t)hh * SQL + s) * HDSZ)
                        : (kbuf + ((size_t)(hh - 32) * SQL + s) * HDSZ);
  u16* pp = base + 2 * p;
  uint32_t packed = *reinterpret_cast<uint32_t*>(pp);
  float x0 = bf2f((u16)(packed & 0xffff));
  float x1 = bf2f((u16)(packed >> 16));
  float o0 = x0 * c - x1 * sn;
  float o1 = x1 * c + x0 * sn;
  *reinterpret_cast<uint32_t*>(pp) = (uint32_t)f2bf(o0) | ((uint32_t)f2bf(o1) << 16);
}

// ---------- flash attention: causal, GQA (g = h>>4), online softmax ----------
// ONE wave per block, QBLK=32 q-rows, KVBLK=64.
// SPLIT=1: KV chunk = 256 (<=4 iterations, near-uniform). Per head:
//   band b = qi>>3 has (b+1) chunks per q-tile -> 288 blocks/head, 9216 total
//   (~3x the 12-wave/CU residency capacity -> scheduler refills, avg occupancy
//   stays near capacity). qi<8 (single chunk) writes ctx directly; others
//   write normalized partial O (bf16) + (m,l); k_merge combines (<=8 partials).
// SPLIT=0: single-pass fallback when ws too small.
#define CHK 256
#define PPH 288      // partial-slots (blocks) per head

template<int SPLIT>
__global__ __launch_bounds__(64)
void k_attn(const u16* __restrict__ qbuf, const u16* __restrict__ kbuf,
            const u16* __restrict__ vtbuf,
            u16* __restrict__ part, float2* __restrict__ mlbuf,
            u16* __restrict__ ctx)
{
  __shared__ __align__(16) u16 pls[32 * 72];   // P tile [32 rows][64 kv + 8 pad]
  const int lane = threadIdx.x;
  const int l15 = lane & 15, lg = lane >> 4;
  const int h = blockIdx.x;
  const int g = h >> 4;                     // n_rep = 16
  int qi, ci, nchk = 1;
  if (SPLIT) {
    int off = blockIdx.y, b = 0;
#pragma unroll
    for (int bb = 0; bb < 8; ++bb) {        // find band: sizes 8,16,...,64
      int bs = 8 * (bb + 1);
      if (off < bs) { b = bb; break; }
      off -= bs;
    }
    nchk = b + 1;
    qi = (b << 3) + off / nchk;
    ci = off % nchk;
  } else {
    qi = (int)gridDim.y - 1 - (int)blockIdx.y;
    ci = 0;
  }
  const int q0 = qi * 32;
  const int E  = q0 + 32;                   // causal extent (exclusive)
  const int c0 = SPLIT ? ci * CHK : 0;
  const int c1 = SPLIT ? min(c0 + CHK, E) : E;
  const float inv_norm = 0.08838834764831845f;   // 1/sqrt(128)

  short8 aq[2][4];
#pragma unroll
  for (int rt = 0; rt < 2; ++rt) {
    const u16* qp = qbuf + ((size_t)h * SQL + q0 + rt * 16 + l15) * HDSZ + lg * 8;
#pragma unroll
    for (int kc = 0; kc < 4; ++kc)
      aq[rt][kc] = *reinterpret_cast<const short8*>(qp + kc * 32);
  }
  f32x4 o[2][8] = {};
  float mrow[2][4], lrow[2][4];
#pragma unroll
  for (int rt = 0; rt < 2; ++rt)
#pragma unroll
    for (int j = 0; j < 4; ++j) { mrow[rt][j] = -__builtin_inff(); lrow[rt][j] = 0.f; }

  for (int j0 = c0; j0 < c1; j0 += 64) {
    short8 bk[4][4];
    const u16* kp = kbuf + ((size_t)g * SQL + j0 + l15) * HDSZ + lg * 8;
#pragma unroll
    for (int kt = 0; kt < 4; ++kt)
#pragma unroll
      for (int kc = 0; kc < 4; ++kc)
        bk[kt][kc] = *reinterpret_cast<const short8*>(kp + (size_t)kt * 16 * HDSZ + kc * 32);

    f32x4 s[2][4] = {};
    __builtin_amdgcn_s_setprio(1);
#pragma unroll
    for (int kc = 0; kc < 4; ++kc)
#pragma unroll
      for (int rt = 0; rt < 2; ++rt)
#pragma unroll
        for (int kt = 0; kt < 4; ++kt)
          s[rt][kt] = __builtin_amdgcn_mfma_f32_16x16x32_bf16(aq[rt][kc], bk[kt][kc], s[rt][kt], 0, 0, 0);
    __builtin_amdgcn_s_setprio(0);

    // V loads issued early: consumed only at PV, latency hides under softmax
    short8 bv[8][2];
    const u16* vp = vtbuf + ((size_t)g * HDSZ + l15) * SQL + j0 + lg * 8;
#pragma unroll
    for (int df = 0; df < 8; ++df)
#pragma unroll
      for (int kc2 = 0; kc2 < 2; ++kc2)
        bv[df][kc2] = *reinterpret_cast<const short8*>(vp + (size_t)df * 16 * SQL + kc2 * 32);

    // softmax: 8 independent chains (rt, j); mask only near the diagonal
    const bool domask = (j0 + 63 > q0);
    float al[2][4];
#pragma unroll
    for (int rt = 0; rt < 2; ++rt) {
#pragma unroll
      for (int j = 0; j < 4; ++j) {
        int row = q0 + rt * 16 + lg * 4 + j;
        float v[4];
        if (domask) {
#pragma unroll
          for (int kt = 0; kt < 4; ++kt)
            v[kt] = (j0 + kt * 16 + l15 > row) ? -1e30f : s[rt][kt][j] * inv_norm;
        } else {
#pragma unroll
          for (int kt = 0; kt < 4; ++kt)
            v[kt] = s[rt][kt][j] * inv_norm;
        }
        float rm = fmaxf(fmaxf(v[0], v[1]), fmaxf(v[2], v[3]));
        rm = fmaxf(rm, __shfl_xor(rm, 1));
        rm = fmaxf(rm, __shfl_xor(rm, 2));
        rm = fmaxf(rm, __shfl_xor(rm, 4));
        rm = fmaxf(rm, __shfl_xor(rm, 8));
        float mn = fmaxf(mrow[rt][j], rm);
        float a = __expf(mrow[rt][j] - mn);     // first tile: exp(-inf)=0
        mrow[rt][j] = mn;
        float p[4], ps = 0.f;
#pragma unroll
        for (int kt = 0; kt < 4; ++kt) { p[kt] = __expf(v[kt] - mn); ps += p[kt]; }
        ps += __shfl_xor(ps, 1);
        ps += __shfl_xor(ps, 2);
        ps += __shfl_xor(ps, 4);
        ps += __shfl_xor(ps, 8);
        lrow[rt][j] = lrow[rt][j] * a + ps;
        al[rt][j] = a;
        int rl = rt * 16 + lg * 4 + j;
#pragma unroll
        for (int kt = 0; kt < 4; ++kt)
          pls[rl * 72 + kt * 16 + l15] = f2bf(p[kt]);
      }
    }
    asm volatile("s_waitcnt lgkmcnt(0)" ::: "memory");  // wave-local P write->read

    short8 ap[2][2];
#pragma unroll
    for (int rt = 0; rt < 2; ++rt)
#pragma unroll
      for (int kc2 = 0; kc2 < 2; ++kc2)
        ap[rt][kc2] = *reinterpret_cast<const short8*>(&pls[(rt * 16 + l15) * 72 + kc2 * 32 + lg * 8]);

    __builtin_amdgcn_s_setprio(1);
#pragma unroll
    for (int rt = 0; rt < 2; ++rt) {
#pragma unroll
      for (int df = 0; df < 8; ++df) {
        f32x4 t = o[rt][df];
        t[0] *= al[rt][0]; t[1] *= al[rt][1]; t[2] *= al[rt][2]; t[3] *= al[rt][3];
        t = __builtin_amdgcn_mfma_f32_16x16x32_bf16(ap[rt][0], bv[df][0], t, 0, 0, 0);
        t = __builtin_amdgcn_mfma_f32_16x16x32_bf16(ap[rt][1], bv[df][1], t, 0, 0, 0);
        o[rt][df] = t;
      }
    }
    __builtin_amdgcn_s_setprio(0);
  }

  if (SPLIT && nchk > 1) {
    const int pid = h * PPH + blockIdx.y;
    u16* pp = part + (size_t)pid * 32 * 128;
#pragma unroll
    for (int rt = 0; rt < 2; ++rt) {
#pragma unroll
      for (int j = 0; j < 4; ++j) {
        float inv_l = 1.0f / lrow[rt][j];
        int rl = rt * 16 + lg * 4 + j;
#pragma unroll
        for (int df = 0; df < 8; ++df)
          pp[rl * 128 + df * 16 + l15] = f2bf(o[rt][df][j] * inv_l);
        if (l15 == 0)
          mlbuf[pid * 32 + rl] = make_float2(mrow[rt][j], lrow[rt][j]);
      }
    }
  } else {
#pragma unroll
    for (int rt = 0; rt < 2; ++rt) {
#pragma unroll
      for (int j = 0; j < 4; ++j) {
        float inv_l = 1.0f / lrow[rt][j];
        int row = q0 + rt * 16 + lg * 4 + j;
        u16* cp = ctx + (size_t)row * QDIM + h * HDSZ;
#pragma unroll
        for (int df = 0; df < 8; ++df)
          cp[df * 16 + l15] = f2bf(o[rt][df][j] * inv_l);
      }
    }
  }
}

// ---------- merge partials (rows with qi>=8 only) ----------
// rows/head = 56*32 = 1792; threads = 32 heads * 1792 * 16 (8 dims each)
__global__ __launch_bounds__(256)
void k_merge(const u16* __restrict__ part, const float2* __restrict__ mlbuf,
             u16* __restrict__ ctx)
{
  int idx = blockIdx.x * 256 + threadIdx.x;
  int d8  = idx & 15;
  int r   = idx >> 4;
  int h   = r / 1792;
  int rr  = r - h * 1792;
  int qi  = 8 + (rr >> 5);
  int rl  = rr & 31;
  int row = qi * 32 + rl;
  int b   = qi >> 3;                 // band 1..7
  int nc  = b + 1;                   // chunks 2..8
  int base = h * PPH + 4 * b * (b + 1) + (qi & 7) * nc;

  float m[8], l[8], M = -__builtin_inff();
  for (int c = 0; c < nc; ++c) {
    float2 ml = mlbuf[(base + c) * 32 + rl];
    m[c] = ml.x; l[c] = ml.y;
    M = fmaxf(M, ml.x);
  }
  float w[8], W = 0.f;
  for (int c = 0; c < nc; ++c) { w[c] = l[c] * __expf(m[c] - M); W += w[c]; }
  float invW = 1.0f / W;

  float acc[8] = {};
  for (int c = 0; c < nc; ++c) {
    short8 p = *reinterpret_cast<const short8*>(
        part + ((size_t)(base + c) * 32 + rl) * 128 + d8 * 8);
    float wc = w[c] * invW;
#pragma unroll
    for (int e = 0; e < 8; ++e)
      acc[e] += wc * bf2f((u16)p[e]);
  }
  short8 o;
#pragma unroll
  for (int e = 0; e < 8; ++e) o[e] = (short)f2bf(acc[e]);
  *reinterpret_cast<short8*>(ctx + (size_t)row * QDIM + h * 128 + d8 * 8) = o;
}

// ---------- workspace layout (bytes) ----------
//  0         : hidden_bf16 [2048][4096]   16777216   (reused as ctx after GEMM1)
//  16777216  : W_bf16      [4608][4096]   37748736   (Wqkv, then Wdense)
//  54525952  : q           [32][2048][128] 16777216
//  71303168  : k           [2][2048][128]   1048576
//  72351744  : vt          [2][128][2048]   1048576
//  73400320  : attn partial O bf16 [9216][32][128]   75497472  (split path)
//  148897792 : attn (m,l) f32x2    [9216][32]         2359296
//  total (split) 151257088; (fallback) 73400320

#define WS_PART 73400320ull
#define WS_ML   148897792ull
#define WS_NEED 151257088ull

extern "C" void kernel_launch(void* const* d_in, const int* in_sizes, int n_in,
                              void* d_out, int out_size, void* d_ws, size_t ws_size,
                              hipStream_t stream) {
  const float* hs     = (const float*)d_in[0];
  const float* wqkv   = (const float*)d_in[1];
  const float* bqkv   = (const float*)d_in[2];
  const float* wdense = (const float*)d_in[3];
  const float* rope   = (const float*)d_in[4];
  char* ws = (char*)d_ws;
  u16* hid_b = (u16*)(ws + 0);
  u16* w_b   = (u16*)(ws + 16777216);
  u16* qb    = (u16*)(ws + 54525952);
  u16* kb    = (u16*)(ws + 71303168);
  u16* vtb   = (u16*)(ws + 72351744);
  u16* part  = (u16*)(ws + WS_PART);
  float2* ml = (float2*)(ws + WS_ML);
  u16* ctx   = hid_b;                      // reuse after GEMM1
  float* outf = (float*)d_out;

  k_cvt<<<2048, 256, 0, stream>>>(hs,   hid_b, SQL * HID / 8);
  k_cvt<<<2048, 256, 0, stream>>>(wqkv, w_b,   QKVD * HID / 8);
  k_gemm<0><<<dim3(QKVD / 128, SQL / 128), 256, 0, stream>>>(
      hid_b, w_b, bqkv, qb, kb, vtb, nullptr);
  k_rope<<<(SQL * 34 * 32) / 256, 256, 0, stream>>>(qb, kb, rope);
  k_cvt<<<2048, 256, 0, stream>>>(wdense, w_b, QDIM * HID / 8);   // after GEMM1
  if (ws_size >= WS_NEED) {
    k_attn<1><<<dim3(NHEADS, PPH), 64, 0, stream>>>(qb, kb, vtb, part, ml, ctx);
    k_merge<<<(NHEADS * 1792 * 16) / 256, 256, 0, stream>>>(part, ml, ctx);
  } else {
    k_attn<0><<<dim3(NHEADS, SQL / 32), 64, 0, stream>>>(qb, kb, vtb, nullptr, nullptr, ctx);
  }
  k_gemm<1><<<dim3(QDIM / 128, SQL / 128), 256, 0, stream>>>(
      ctx, w_b, nullptr, nullptr, nullptr, nullptr, outf);
}

// Round 10
// 335.045 us; speedup vs baseline: 1.2212x; 1.2212x over previous
//
#include <hip/hip_runtime.h>
#include <stdint.h>

#define SQL 2048
#define HID 4096
#define NHEADS 32
#define HDSZ 128
#define QKVD 4608
#define QDIM 4096

typedef unsigned short u16;
typedef __attribute__((ext_vector_type(8))) short short8;
typedef __attribute__((ext_vector_type(4))) float f32x4;

#define AS1(p) ((__attribute__((address_space(1))) void*)(p))
#define AS3(p) ((__attribute__((address_space(3))) void*)(p))

__device__ __forceinline__ float bf2f(u16 u) {
  return __uint_as_float(((uint32_t)u) << 16);
}
__device__ __forceinline__ u16 f2bf(float f) {
  uint32_t x = __float_as_uint(f);
  x += 0x7fffu + ((x >> 16) & 1u);
  return (u16)(x >> 16);
}

// ---------- fp32 -> bf16 convert, 8 elems/thread ----------
__global__ void k_cvt(const float* __restrict__ in, u16* __restrict__ out, int n8) {
  int i = blockIdx.x * blockDim.x + threadIdx.x;
  int stride = gridDim.x * blockDim.x;
  for (; i < n8; i += stride) {
    const float4* p = reinterpret_cast<const float4*>(in) + (size_t)i * 2;
    float4 a = p[0], b = p[1];
    short8 o;
    o[0] = (short)f2bf(a.x); o[1] = (short)f2bf(a.y);
    o[2] = (short)f2bf(a.z); o[3] = (short)f2bf(a.w);
    o[4] = (short)f2bf(b.x); o[5] = (short)f2bf(b.y);
    o[6] = (short)f2bf(b.z); o[7] = (short)f2bf(b.w);
    reinterpret_cast<short8*>(out)[i] = o;
  }
}

// ---------- GEMM C[M][N] = A[M][K] * B[N][K]^T, bf16 MFMA ----------
// MODE 0: qkv epilogue (bias + 1/sqrt(d) on q + scatter to q/k/vt).
// MODE 1: fp32 C store.
template<int MODE>
__global__ __launch_bounds__(256, 2)
void k_gemm(const u16* __restrict__ A, const u16* __restrict__ B,
            const float* __restrict__ bias,
            u16* __restrict__ qbuf, u16* __restrict__ kbuf, u16* __restrict__ vtbuf,
            float* __restrict__ outf)
{
  __shared__ __align__(16) u16 ldsA[128 * 64];
  __shared__ __align__(16) u16 ldsB[128 * 64];
  const int tid = threadIdx.x;
  const int wid = tid >> 6, lane = tid & 63;
  const int l15 = lane & 15, lg = lane >> 4;
  const int m0 = blockIdx.y * 128, n0 = blockIdx.x * 128;
  const int wr = wid >> 1, wc = wid & 1;

  f32x4 acc[4][4] = {};

  const int srow = lane >> 3;                      // row within 8-row segment
  const int skb  = (((lane & 7) ^ srow) << 4);     // pre-swizzled source byte
  const size_t rowbytes = (size_t)HID * 2;

  for (int t = 0; t < HID / 64; ++t) {
    __syncthreads();
    const char* Ab = (const char*)A + (size_t)m0 * rowbytes + (size_t)t * 128;
    const char* Bb = (const char*)B + (size_t)n0 * rowbytes + (size_t)t * 128;
#pragma unroll
    for (int i = 0; i < 4; ++i) {
      int seg = i * 4 + wid;
      int row = seg * 8 + srow;
      __builtin_amdgcn_global_load_lds(AS1(Ab + (size_t)row * rowbytes + skb),
                                       AS3(ldsA + seg * 512), 16, 0, 0);
      __builtin_amdgcn_global_load_lds(AS1(Bb + (size_t)row * rowbytes + skb),
                                       AS3(ldsB + seg * 512), 16, 0, 0);
    }
    __syncthreads();
#pragma unroll
    for (int kc = 0; kc < 2; ++kc) {
      short8 af[4], bfr[4];
#pragma unroll
      for (int mi = 0; mi < 4; ++mi) {
        int row = wr * 64 + mi * 16 + l15;
        int kb = (kc * 64 + lg * 16) ^ ((row & 7) << 4);
        af[mi] = *reinterpret_cast<const short8*>((const char*)ldsA + row * 128 + kb);
      }
#pragma unroll
      for (int ni = 0; ni < 4; ++ni) {
        int row = wc * 64 + ni * 16 + l15;
        int kb = (kc * 64 + lg * 16) ^ ((row & 7) << 4);
        bfr[ni] = *reinterpret_cast<const short8*>((const char*)ldsB + row * 128 + kb);
      }
#pragma unroll
      for (int mi = 0; mi < 4; ++mi)
#pragma unroll
        for (int ni = 0; ni < 4; ++ni)
          acc[mi][ni] = __builtin_amdgcn_mfma_f32_16x16x32_bf16(af[mi], bfr[ni], acc[mi][ni], 0, 0, 0);
    }
  }

#pragma unroll
  for (int mi = 0; mi < 4; ++mi) {
#pragma unroll
    for (int ni = 0; ni < 4; ++ni) {
      int row0 = m0 + wr * 64 + mi * 16 + lg * 4;
      int col  = n0 + wc * 64 + ni * 16 + l15;
      if (MODE == 0) {
        float bv = bias[col];
#pragma unroll
        for (int j = 0; j < 4; ++j) {
          float v = acc[mi][ni][j] + bv;
          int r = row0 + j;
          if (col < QDIM) {
            v *= 0.08838834764831845f;       // fold 1/sqrt(128) into q
            int hh = col >> 7, d = col & 127;
            qbuf[((size_t)hh * SQL + r) * HDSZ + d] = f2bf(v);
          } else if (col < QDIM + 256) {
            int c2 = col - QDIM; int g = c2 >> 7, d = c2 & 127;
            kbuf[((size_t)g * SQL + r) * HDSZ + d] = f2bf(v);
          } else {
            int c2 = col - QDIM - 256; int g = c2 >> 7, d = c2 & 127;
            vtbuf[((size_t)g * HDSZ + d) * SQL + r] = f2bf(v);   // V transposed
          }
        }
      } else {
#pragma unroll
        for (int j = 0; j < 4; ++j)
          outf[(size_t)(row0 + j) * QDIM + col] = acc[mi][ni][j];
      }
    }
  }
}

// ---------- RoPE (interleaved pairs, first 64 dims), in place on q and k ----------
__global__ void k_rope(u16* __restrict__ qbuf, u16* __restrict__ kbuf,
                       const float* __restrict__ rope) {
  int idx = blockIdx.x * blockDim.x + threadIdx.x;
  if (idx >= SQL * 34 * 32) return;
  int p = idx & 31;
  int hh = (idx >> 5) % 34;
  int s = idx / (34 * 32);
  float c  = rope[s * 64 + p * 2 + 0];
  float sn = rope[s * 64 + p * 2 + 1];
  u16* base = (hh < 32) ? (qbuf + ((size_t)hh * SQL + s) * HDSZ)
                        : (kbuf + ((size_t)(hh - 32) * SQL + s) * HDSZ);
  u16* pp = base + 2 * p;
  uint32_t packed = *reinterpret_cast<uint32_t*>(pp);
  float x0 = bf2f((u16)(packed & 0xffff));
  float x1 = bf2f((u16)(packed >> 16));
  float o0 = x0 * c - x1 * sn;
  float o1 = x1 * c + x0 * sn;
  *reinterpret_cast<uint32_t*>(pp) = (uint32_t)f2bf(o0) | ((uint32_t)f2bf(o1) << 16);
}

// ---------- flash attention: causal GQA, swapped-QK softmax ----------
// ONE wave per block, QBLK=32 q-rows, KVBLK=64. grid (NHEADS, 64), qi reversed.
// QK^T computed SWAPPED: st = mfma(A=K, B=Q) -> S^T with col=q=lane&15.
// Each q-row's 64 kv values live in the 4 lanes sharing l15 (lg=0..3, 16 regs
// each): softmax = in-lane tree + TWO shfl_xor (16,32) for max and sum
// (8 shfls/tile vs 64 in the row-major scheme).
//  - causal mask by register index (kv = j0+16kt+4lg+j vs q=l15)
//  - defer-rescale (T13): skip O-rescale unless !__all(rm <= m+8)
//  - P packed to bf16 words (v_cvt_pk_bf16_f32), transposed via padded LDS
//    ([32][36] words -> 2-way banks = free), read back as PV A-fragments.
// 1/sqrt(d) pre-folded into q by GEMM1 epilogue.
__global__ __launch_bounds__(64)
void k_attn(const u16* __restrict__ qbuf, const u16* __restrict__ kbuf,
            const u16* __restrict__ vtbuf, u16* __restrict__ ctx)
{
  __shared__ uint32_t plw[32][36];   // P words: row=q_local, word=kv pair
  const int lane = threadIdx.x;
  const int l15 = lane & 15, lg = lane >> 4;
  const int h = blockIdx.x;
  const int g = h >> 4;                     // n_rep = 16
  const int qi = (int)gridDim.y - 1 - (int)blockIdx.y;
  const int q0 = qi * 32;

  short8 aq[2][4];
#pragma unroll
  for (int rt = 0; rt < 2; ++rt) {
    const u16* qp = qbuf + ((size_t)h * SQL + q0 + rt * 16 + l15) * HDSZ + lg * 8;
#pragma unroll
    for (int kc = 0; kc < 4; ++kc)
      aq[rt][kc] = *reinterpret_cast<const short8*>(qp + kc * 32);
  }
  f32x4 o[2][8] = {};
  float mrow[2], lrow[2];
#pragma unroll
  for (int rt = 0; rt < 2; ++rt) { mrow[rt] = -__builtin_inff(); lrow[rt] = 0.f; }

  const int jend = q0 + 31;
  for (int j0 = 0; j0 <= jend; j0 += 64) {
    // K tile loads (A-fragments: row=kv=l15, k=d)
    short8 bk[4][4];
    const u16* kp = kbuf + ((size_t)g * SQL + j0 + l15) * HDSZ + lg * 8;
#pragma unroll
    for (int kt = 0; kt < 4; ++kt)
#pragma unroll
      for (int kc = 0; kc < 4; ++kc)
        bk[kt][kc] = *reinterpret_cast<const short8*>(kp + (size_t)kt * 16 * HDSZ + kc * 32);

    // swapped QK^T: st[rt][kt] = K_tile(kt) x Q^T(rt); lane: col=q=l15, row=kv
    f32x4 st[2][4] = {};
    __builtin_amdgcn_s_setprio(1);
#pragma unroll
    for (int kc = 0; kc < 4; ++kc)
#pragma unroll
      for (int rt = 0; rt < 2; ++rt)
#pragma unroll
        for (int kt = 0; kt < 4; ++kt)
          st[rt][kt] = __builtin_amdgcn_mfma_f32_16x16x32_bf16(bk[kt][kc], aq[rt][kc], st[rt][kt], 0, 0, 0);
    __builtin_amdgcn_s_setprio(0);

    // V loads issued early: consumed only at PV, latency hides under softmax
    short8 bv[8][2];
    const u16* vp = vtbuf + ((size_t)g * HDSZ + l15) * SQL + j0 + lg * 8;
#pragma unroll
    for (int df = 0; df < 8; ++df)
#pragma unroll
      for (int kc2 = 0; kc2 < 2; ++kc2)
        bv[df][kc2] = *reinterpret_cast<const short8*>(vp + (size_t)df * 16 * SQL + kc2 * 32);

    // softmax: one q-row per l15; 4 lanes (lg=0..3) hold 16 kv values each
    const bool domask = (j0 + 63 > q0);
#pragma unroll
    for (int rt = 0; rt < 2; ++rt) {
      const int q = q0 + rt * 16 + l15;
      float p[4][4];
#pragma unroll
      for (int kt = 0; kt < 4; ++kt)
#pragma unroll
        for (int j = 0; j < 4; ++j) {
          float v = st[rt][kt][j];
          if (domask) {
            int kvi = j0 + kt * 16 + lg * 4 + j;
            v = (kvi > q) ? -1e30f : v;
          }
          p[kt][j] = v;
        }
      float rm = fmaxf(fmaxf(fmaxf(p[0][0], p[0][1]), fmaxf(p[0][2], p[0][3])),
                       fmaxf(fmaxf(p[1][0], p[1][1]), fmaxf(p[1][2], p[1][3])));
      rm = fmaxf(rm, fmaxf(fmaxf(fmaxf(p[2][0], p[2][1]), fmaxf(p[2][2], p[2][3])),
                           fmaxf(fmaxf(p[3][0], p[3][1]), fmaxf(p[3][2], p[3][3]))));
      // cross-lg reduction: full row max lives across lanes l15, l15+16, +32, +48
      rm = fmaxf(rm, __shfl_xor(rm, 16));
      rm = fmaxf(rm, __shfl_xor(rm, 32));
      if (!__all(rm <= mrow[rt] + 8.0f)) {        // defer-rescale (T13)
        float mn = fmaxf(mrow[rt], rm);
        float a = __expf(mrow[rt] - mn);          // first tile: exp(-inf)=0
        mrow[rt] = mn;
        lrow[rt] *= a;
        float ar[4];
#pragma unroll
        for (int j = 0; j < 4; ++j) ar[j] = __shfl(a, lg * 4 + j);
#pragma unroll
        for (int df = 0; df < 8; ++df) {
          o[rt][df][0] *= ar[0]; o[rt][df][1] *= ar[1];
          o[rt][df][2] *= ar[2]; o[rt][df][3] *= ar[3];
        }
      }
      float ps = 0.f;
#pragma unroll
      for (int kt = 0; kt < 4; ++kt)
#pragma unroll
        for (int j = 0; j < 4; ++j) {
          p[kt][j] = __expf(p[kt][j] - mrow[rt]);
          ps += p[kt][j];
        }
      // cross-lg reduction for the row sum
      ps += __shfl_xor(ps, 16);
      ps += __shfl_xor(ps, 32);
      lrow[rt] += ps;
      // pack P to bf16 words, transpose through LDS: word w holds kv pair 2w
#pragma unroll
      for (int kt = 0; kt < 4; ++kt)
#pragma unroll
        for (int u = 0; u < 2; ++u) {
          uint32_t W;
          asm("v_cvt_pk_bf16_f32 %0, %1, %2"
              : "=v"(W) : "v"(p[kt][2 * u]), "v"(p[kt][2 * u + 1]));
          plw[rt * 16 + l15][8 * kt + 2 * lg + u] = W;
        }
    }
    asm volatile("s_waitcnt lgkmcnt(0)" ::: "memory");  // wave-local write->read

    // PV A-fragments: lane row=q_local=l15, k=kv=8*lg+e (per 32-kv half kc2)
    short8 ap[2][2];
#pragma unroll
    for (int rt = 0; rt < 2; ++rt)
#pragma unroll
      for (int kc2 = 0; kc2 < 2; ++kc2)
        ap[rt][kc2] = *reinterpret_cast<const short8*>(&plw[rt * 16 + l15][16 * kc2 + 4 * lg]);

    __builtin_amdgcn_s_setprio(1);
#pragma unroll
    for (int rt = 0; rt < 2; ++rt) {
#pragma unroll
      for (int df = 0; df < 8; ++df) {
        f32x4 t = o[rt][df];
        t = __builtin_amdgcn_mfma_f32_16x16x32_bf16(ap[rt][0], bv[df][0], t, 0, 0, 0);
        t = __builtin_amdgcn_mfma_f32_16x16x32_bf16(ap[rt][1], bv[df][1], t, 0, 0, 0);
        o[rt][df] = t;
      }
    }
    __builtin_amdgcn_s_setprio(0);
  }

  // epilogue: O rows have q=q0+16rt+4lg+j; l lives at lane l15=q_local -> shfl
#pragma unroll
  for (int rt = 0; rt < 2; ++rt) {
    float linv[4];
#pragma unroll
    for (int j = 0; j < 4; ++j) linv[j] = 1.0f / __shfl(lrow[rt], lg * 4 + j);
#pragma unroll
    for (int j = 0; j < 4; ++j) {
      int row = q0 + rt * 16 + lg * 4 + j;
      u16* cp = ctx + (size_t)row * QDIM + h * HDSZ;
#pragma unroll
      for (int df = 0; df < 8; ++df)
        cp[df * 16 + l15] = f2bf(o[rt][df][j] * linv[j]);
    }
  }
}

// ---------- workspace layout (bytes) ----------
//  0        : hidden_bf16 [2048][4096]   16777216   (reused as ctx after GEMM1)
//  16777216 : W_bf16      [4608][4096]   37748736   (Wqkv, then Wdense)
//  54525952 : q           [32][2048][128] 16777216
//  71303168 : k           [2][2048][128]   1048576
//  72351744 : vt          [2][128][2048]   1048576
//  total 73400320

extern "C" void kernel_launch(void* const* d_in, const int* in_sizes, int n_in,
                              void* d_out, int out_size, void* d_ws, size_t ws_size,
                              hipStream_t stream) {
  const float* hs     = (const float*)d_in[0];
  const float* wqkv   = (const float*)d_in[1];
  const float* bqkv   = (const float*)d_in[2];
  const float* wdense = (const float*)d_in[3];
  const float* rope   = (const float*)d_in[4];
  char* ws = (char*)d_ws;
  u16* hid_b = (u16*)(ws + 0);
  u16* w_b   = (u16*)(ws + 16777216);
  u16* qb    = (u16*)(ws + 54525952);
  u16* kb    = (u16*)(ws + 71303168);
  u16* vtb   = (u16*)(ws + 72351744);
  u16* ctx   = hid_b;                      // reuse after GEMM1
  float* outf = (float*)d_out;

  k_cvt<<<2048, 256, 0, stream>>>(hs,   hid_b, SQL * HID / 8);
  k_cvt<<<2048, 256, 0, stream>>>(wqkv, w_b,   QKVD * HID / 8);
  k_gemm<0><<<dim3(QKVD / 128, SQL / 128), 256, 0, stream>>>(
      hid_b, w_b, bqkv, qb, kb, vtb, nullptr);
  k_rope<<<(SQL * 34 * 32) / 256, 256, 0, stream>>>(qb, kb, rope);
  k_cvt<<<2048, 256, 0, stream>>>(wdense, w_b, QDIM * HID / 8);   // after GEMM1
  k_attn<<<dim3(NHEADS, SQL / 32), 64, 0, stream>>>(qb, kb, vtb, ctx);
  k_gemm<1><<<dim3(QDIM / 128, SQL / 128), 256, 0, stream>>>(
      ctx, w_b, nullptr, nullptr, nullptr, nullptr, outf);
}

// Round 11
// 304.179 us; speedup vs baseline: 1.3451x; 1.1015x over previous
//
#include <hip/hip_runtime.h>
#include <stdint.h>

#define SQL 2048
#define HID 4096
#define NHEADS 32
#define HDSZ 128
#define QKVD 4608
#define QDIM 4096

typedef unsigned short u16;
typedef __attribute__((ext_vector_type(8))) short short8;
typedef __attribute__((ext_vector_type(4))) float f32x4;

#define AS1(p) ((__attribute__((address_space(1))) void*)(p))
#define AS3(p) ((__attribute__((address_space(3))) void*)(p))

__device__ __forceinline__ float bf2f(u16 u) {
  return __uint_as_float(((uint32_t)u) << 16);
}
__device__ __forceinline__ u16 f2bf(float f) {
  uint32_t x = __float_as_uint(f);
  x += 0x7fffu + ((x >> 16) & 1u);
  return (u16)(x >> 16);
}

// ---------- fp32 -> bf16 convert, 8 elems/thread ----------
__global__ void k_cvt(const float* __restrict__ in, u16* __restrict__ out, int n8) {
  int i = blockIdx.x * blockDim.x + threadIdx.x;
  int stride = gridDim.x * blockDim.x;
  for (; i < n8; i += stride) {
    const float4* p = reinterpret_cast<const float4*>(in) + (size_t)i * 2;
    float4 a = p[0], b = p[1];
    short8 o;
    o[0] = (short)f2bf(a.x); o[1] = (short)f2bf(a.y);
    o[2] = (short)f2bf(a.z); o[3] = (short)f2bf(a.w);
    o[4] = (short)f2bf(b.x); o[5] = (short)f2bf(b.y);
    o[6] = (short)f2bf(b.z); o[7] = (short)f2bf(b.w);
    reinterpret_cast<short8*>(out)[i] = o;
  }
}

// ---------- GEMM C[M][N] = A[M][K] * B[N][K]^T, bf16 MFMA ----------
// MODE 0: qkv epilogue (bias + 1/sqrt(d) on q + scatter to q/k/vt).
// MODE 1: fp32 C store.
template<int MODE>
__global__ __launch_bounds__(256, 2)
void k_gemm(const u16* __restrict__ A, const u16* __restrict__ B,
            const float* __restrict__ bias,
            u16* __restrict__ qbuf, u16* __restrict__ kbuf, u16* __restrict__ vtbuf,
            float* __restrict__ outf)
{
  __shared__ __align__(16) u16 ldsA[128 * 64];
  __shared__ __align__(16) u16 ldsB[128 * 64];
  const int tid = threadIdx.x;
  const int wid = tid >> 6, lane = tid & 63;
  const int l15 = lane & 15, lg = lane >> 4;
  const int m0 = blockIdx.y * 128, n0 = blockIdx.x * 128;
  const int wr = wid >> 1, wc = wid & 1;

  f32x4 acc[4][4] = {};

  const int srow = lane >> 3;                      // row within 8-row segment
  const int skb  = (((lane & 7) ^ srow) << 4);     // pre-swizzled source byte
  const size_t rowbytes = (size_t)HID * 2;

  for (int t = 0; t < HID / 64; ++t) {
    __syncthreads();
    const char* Ab = (const char*)A + (size_t)m0 * rowbytes + (size_t)t * 128;
    const char* Bb = (const char*)B + (size_t)n0 * rowbytes + (size_t)t * 128;
#pragma unroll
    for (int i = 0; i < 4; ++i) {
      int seg = i * 4 + wid;
      int row = seg * 8 + srow;
      __builtin_amdgcn_global_load_lds(AS1(Ab + (size_t)row * rowbytes + skb),
                                       AS3(ldsA + seg * 512), 16, 0, 0);
      __builtin_amdgcn_global_load_lds(AS1(Bb + (size_t)row * rowbytes + skb),
                                       AS3(ldsB + seg * 512), 16, 0, 0);
    }
    __syncthreads();
#pragma unroll
    for (int kc = 0; kc < 2; ++kc) {
      short8 af[4], bfr[4];
#pragma unroll
      for (int mi = 0; mi < 4; ++mi) {
        int row = wr * 64 + mi * 16 + l15;
        int kb = (kc * 64 + lg * 16) ^ ((row & 7) << 4);
        af[mi] = *reinterpret_cast<const short8*>((const char*)ldsA + row * 128 + kb);
      }
#pragma unroll
      for (int ni = 0; ni < 4; ++ni) {
        int row = wc * 64 + ni * 16 + l15;
        int kb = (kc * 64 + lg * 16) ^ ((row & 7) << 4);
        bfr[ni] = *reinterpret_cast<const short8*>((const char*)ldsB + row * 128 + kb);
      }
#pragma unroll
      for (int mi = 0; mi < 4; ++mi)
#pragma unroll
        for (int ni = 0; ni < 4; ++ni)
          acc[mi][ni] = __builtin_amdgcn_mfma_f32_16x16x32_bf16(af[mi], bfr[ni], acc[mi][ni], 0, 0, 0);
    }
  }

#pragma unroll
  for (int mi = 0; mi < 4; ++mi) {
#pragma unroll
    for (int ni = 0; ni < 4; ++ni) {
      int row0 = m0 + wr * 64 + mi * 16 + lg * 4;
      int col  = n0 + wc * 64 + ni * 16 + l15;
      if (MODE == 0) {
        float bv = bias[col];
#pragma unroll
        for (int j = 0; j < 4; ++j) {
          float v = acc[mi][ni][j] + bv;
          int r = row0 + j;
          if (col < QDIM) {
            v *= 0.08838834764831845f;       // fold 1/sqrt(128) into q
            int hh = col >> 7, d = col & 127;
            qbuf[((size_t)hh * SQL + r) * HDSZ + d] = f2bf(v);
          } else if (col < QDIM + 256) {
            int c2 = col - QDIM; int g = c2 >> 7, d = c2 & 127;
            kbuf[((size_t)g * SQL + r) * HDSZ + d] = f2bf(v);
          } else {
            int c2 = col - QDIM - 256; int g = c2 >> 7, d = c2 & 127;
            vtbuf[((size_t)g * HDSZ + d) * SQL + r] = f2bf(v);   // V transposed
          }
        }
      } else {
#pragma unroll
        for (int j = 0; j < 4; ++j)
          outf[(size_t)(row0 + j) * QDIM + col] = acc[mi][ni][j];
      }
    }
  }
}

// ---------- RoPE (interleaved pairs, first 64 dims), in place on q and k ----------
__global__ void k_rope(u16* __restrict__ qbuf, u16* __restrict__ kbuf,
                       const float* __restrict__ rope) {
  int idx = blockIdx.x * blockDim.x + threadIdx.x;
  if (idx >= SQL * 34 * 32) return;
  int p = idx & 31;
  int hh = (idx >> 5) % 34;
  int s = idx / (34 * 32);
  float c  = rope[s * 64 + p * 2 + 0];
  float sn = rope[s * 64 + p * 2 + 1];
  u16* base = (hh < 32) ? (qbuf + ((size_t)hh * SQL + s) * HDSZ)
                        : (kbuf + ((size_t)(hh - 32) * SQL + s) * HDSZ);
  u16* pp = base + 2 * p;
  uint32_t packed = *reinterpret_cast<uint32_t*>(pp);
  float x0 = bf2f((u16)(packed & 0xffff));
  float x1 = bf2f((u16)(packed >> 16));
  float o0 = x0 * c - x1 * sn;
  float o1 = x1 * c + x0 * sn;
  *reinterpret_cast<uint32_t*>(pp) = (uint32_t)f2bf(o0) | ((uint32_t)f2bf(o1) << 16);
}

// ---------- flash attention: 8-wave cooperative, LDS-staged K/V ----------
// Block = 512 threads (8 waves), one head h, stripe b = blockIdx.y (0..7).
// Wave w owns q-rows [256w + 32b, +32)  -> every block has the SAME total
// causal work (perfect balance); grid = 32 heads x 8 = 256 blocks = 1/CU.
// K tile [64 kv][128 d] and V^T tile [128 d][64 kv] double-buffered in LDS,
// staged via global_load_lds(16B) with pre-swizzled source + XOR read
// (k_gemm's verified recipe). Pipeline: STAGE(i+1) issued before COMPUTE(i),
// one barrier per iter (T3 minimum).
// Per-wave compute = R10's verified swapped-QK in-register softmax.
__global__ __launch_bounds__(512, 2)
void k_attn(const u16* __restrict__ qbuf, const u16* __restrict__ kbuf,
            const u16* __restrict__ vtbuf, u16* __restrict__ ctx)
{
  __shared__ __align__(16) u16 KL[2][64 * 128];     // 2 x 16 KB
  __shared__ __align__(16) u16 VL[2][128 * 64];     // 2 x 16 KB
  __shared__ uint32_t plw[8][32][36];               // per-wave P transpose
  const int tid = threadIdx.x;
  const int wid = tid >> 6, lane = tid & 63;
  const int l15 = lane & 15, lg = lane >> 4;
  const int h = blockIdx.x;
  const int g = h >> 4;                     // n_rep = 16
  const int bq = blockIdx.y;                // stripe 0..7
  const int q0 = wid * 256 + bq * 32;       // this wave's q-tile
  const int ext = q0 + 32;                  // causal extent (exclusive)
  const int NT = (1824 + 32 * bq + 63) >> 6;  // tiles to stage (max ext/64)

  // staging geometry (per thread, 2 chunks of 16B per tile per buffer)
  const int cA = tid, cB = tid + 512;
  const int krA = cA >> 4, kiA = (cA & 15) ^ (krA & 7);
  const int krB = cB >> 4, kiB = (cB & 15) ^ (krB & 7);
  const int vrA = cA >> 3, viA = (cA & 7) ^ (vrA & 7);
  const int vrB = cB >> 3, viB = (cB & 7) ^ (vrB & 7);
  const char* kg = (const char*)(kbuf + (size_t)g * SQL * HDSZ);
  const char* vg = (const char*)(vtbuf + (size_t)g * HDSZ * SQL);

#define STAGE(t, b)                                                             \
  do {                                                                          \
    int j0s = (t) * 64;                                                         \
    __builtin_amdgcn_global_load_lds(AS1(kg + (size_t)(j0s + krA) * 256 + (kiA << 4)), \
                                     AS3((char*)KL[b] + cA * 16), 16, 0, 0);    \
    __builtin_amdgcn_global_load_lds(AS1(kg + (size_t)(j0s + krB) * 256 + (kiB << 4)), \
                                     AS3((char*)KL[b] + cB * 16), 16, 0, 0);    \
    __builtin_amdgcn_global_load_lds(AS1(vg + (size_t)vrA * (SQL * 2) + j0s * 2 + (viA << 4)), \
                                     AS3((char*)VL[b] + cA * 16), 16, 0, 0);    \
    __builtin_amdgcn_global_load_lds(AS1(vg + (size_t)vrB * (SQL * 2) + j0s * 2 + (viB << 4)), \
                                     AS3((char*)VL[b] + cB * 16), 16, 0, 0);    \
  } while (0)

  short8 aq[2][4];
#pragma unroll
  for (int rt = 0; rt < 2; ++rt) {
    const u16* qp = qbuf + ((size_t)h * SQL + q0 + rt * 16 + l15) * HDSZ + lg * 8;
#pragma unroll
    for (int kc = 0; kc < 4; ++kc)
      aq[rt][kc] = *reinterpret_cast<const short8*>(qp + kc * 32);
  }
  f32x4 o[2][8] = {};
  float mrow[2], lrow[2];
#pragma unroll
  for (int rt = 0; rt < 2; ++rt) { mrow[rt] = -__builtin_inff(); lrow[rt] = 0.f; }

  STAGE(0, 0);
  __syncthreads();

  for (int i = 0; i < NT; ++i) {
    const int cur = i & 1;
    if (i + 1 < NT) STAGE(i + 1, cur ^ 1);

    const int j0 = i * 64;
    if (j0 < ext) {
      const char* kb0 = (const char*)KL[cur];
      const char* vb0 = (const char*)VL[cur];
      const int swz = (l15 & 7) << 4;

      // swapped QK^T with lazy K-fragment reads
      f32x4 st[2][4] = {};
#pragma unroll
      for (int kc = 0; kc < 4; ++kc) {
        short8 bk4[4];
#pragma unroll
        for (int kt = 0; kt < 4; ++kt) {
          int r = 16 * kt + l15;
          bk4[kt] = *reinterpret_cast<const short8*>(
              kb0 + r * 256 + ((kc * 64 + lg * 16) ^ swz));
        }
        __builtin_amdgcn_s_setprio(1);
#pragma unroll
        for (int rt = 0; rt < 2; ++rt)
#pragma unroll
          for (int kt = 0; kt < 4; ++kt)
            st[rt][kt] = __builtin_amdgcn_mfma_f32_16x16x32_bf16(bk4[kt], aq[rt][kc], st[rt][kt], 0, 0, 0);
        __builtin_amdgcn_s_setprio(0);
      }

      // softmax: one q-row per l15; 4 lanes (lg) hold 16 kv values each
      const bool domask = (j0 + 63 > q0);
#pragma unroll
      for (int rt = 0; rt < 2; ++rt) {
        const int q = q0 + rt * 16 + l15;
        float p[4][4];
#pragma unroll
        for (int kt = 0; kt < 4; ++kt)
#pragma unroll
          for (int j = 0; j < 4; ++j) {
            float v = st[rt][kt][j];
            if (domask) {
              int kvi = j0 + kt * 16 + lg * 4 + j;
              v = (kvi > q) ? -1e30f : v;
            }
            p[kt][j] = v;
          }
        float rm = fmaxf(fmaxf(fmaxf(p[0][0], p[0][1]), fmaxf(p[0][2], p[0][3])),
                         fmaxf(fmaxf(p[1][0], p[1][1]), fmaxf(p[1][2], p[1][3])));
        rm = fmaxf(rm, fmaxf(fmaxf(fmaxf(p[2][0], p[2][1]), fmaxf(p[2][2], p[2][3])),
                             fmaxf(fmaxf(p[3][0], p[3][1]), fmaxf(p[3][2], p[3][3]))));
        rm = fmaxf(rm, __shfl_xor(rm, 16));
        rm = fmaxf(rm, __shfl_xor(rm, 32));
        if (!__all(rm <= mrow[rt] + 8.0f)) {        // defer-rescale (T13)
          float mn = fmaxf(mrow[rt], rm);
          float a = __expf(mrow[rt] - mn);          // first tile: exp(-inf)=0
          mrow[rt] = mn;
          lrow[rt] *= a;
          float ar[4];
#pragma unroll
          for (int j = 0; j < 4; ++j) ar[j] = __shfl(a, lg * 4 + j);
#pragma unroll
          for (int df = 0; df < 8; ++df) {
            o[rt][df][0] *= ar[0]; o[rt][df][1] *= ar[1];
            o[rt][df][2] *= ar[2]; o[rt][df][3] *= ar[3];
          }
        }
        float ps = 0.f;
#pragma unroll
        for (int kt = 0; kt < 4; ++kt)
#pragma unroll
          for (int j = 0; j < 4; ++j) {
            p[kt][j] = __expf(p[kt][j] - mrow[rt]);
            ps += p[kt][j];
          }
        ps += __shfl_xor(ps, 16);
        ps += __shfl_xor(ps, 32);
        lrow[rt] += ps;
#pragma unroll
        for (int kt = 0; kt < 4; ++kt)
#pragma unroll
          for (int u = 0; u < 2; ++u) {
            uint32_t W;
            asm("v_cvt_pk_bf16_f32 %0, %1, %2"
                : "=v"(W) : "v"(p[kt][2 * u]), "v"(p[kt][2 * u + 1]));
            plw[wid][rt * 16 + l15][8 * kt + 2 * lg + u] = W;
          }
      }
      asm volatile("s_waitcnt lgkmcnt(0)" ::: "memory");  // wave-local write->read

      short8 ap[2][2];
#pragma unroll
      for (int rt = 0; rt < 2; ++rt)
#pragma unroll
        for (int kc2 = 0; kc2 < 2; ++kc2)
          ap[rt][kc2] = *reinterpret_cast<const short8*>(&plw[wid][rt * 16 + l15][16 * kc2 + 4 * lg]);

      __builtin_amdgcn_s_setprio(1);
#pragma unroll
      for (int df = 0; df < 8; ++df) {
        short8 bv0, bv1;
        int rv = l15 + 16 * df;
#pragma unroll
        for (int kc2 = 0; kc2 < 2; ++kc2) {
          short8 bvv = *reinterpret_cast<const short8*>(
              vb0 + rv * 128 + ((kc2 * 64 + lg * 16) ^ swz));
          if (kc2 == 0) bv0 = bvv; else bv1 = bvv;
        }
#pragma unroll
        for (int rt = 0; rt < 2; ++rt) {
          f32x4 t = o[rt][df];
          t = __builtin_amdgcn_mfma_f32_16x16x32_bf16(ap[rt][0], bv0, t, 0, 0, 0);
          t = __builtin_amdgcn_mfma_f32_16x16x32_bf16(ap[rt][1], bv1, t, 0, 0, 0);
          o[rt][df] = t;
        }
      }
      __builtin_amdgcn_s_setprio(0);
    }
    __syncthreads();
  }

  // epilogue: O rows have q=q0+16rt+4lg+j; l lives at lane l15=q_local -> shfl
#pragma unroll
  for (int rt = 0; rt < 2; ++rt) {
    float linv[4];
#pragma unroll
    for (int j = 0; j < 4; ++j) linv[j] = 1.0f / __shfl(lrow[rt], lg * 4 + j);
#pragma unroll
    for (int j = 0; j < 4; ++j) {
      int row = q0 + rt * 16 + lg * 4 + j;
      u16* cp = ctx + (size_t)row * QDIM + h * HDSZ;
#pragma unroll
      for (int df = 0; df < 8; ++df)
        cp[df * 16 + l15] = f2bf(o[rt][df][j] * linv[j]);
    }
  }
#undef STAGE
}

// ---------- workspace layout (bytes) ----------
//  0        : hidden_bf16 [2048][4096]   16777216   (reused as ctx after GEMM1)
//  16777216 : W_bf16      [4608][4096]   37748736   (Wqkv, then Wdense)
//  54525952 : q           [32][2048][128] 16777216
//  71303168 : k           [2][2048][128]   1048576
//  72351744 : vt          [2][128][2048]   1048576
//  total 73400320

extern "C" void kernel_launch(void* const* d_in, const int* in_sizes, int n_in,
                              void* d_out, int out_size, void* d_ws, size_t ws_size,
                              hipStream_t stream) {
  const float* hs     = (const float*)d_in[0];
  const float* wqkv   = (const float*)d_in[1];
  const float* bqkv   = (const float*)d_in[2];
  const float* wdense = (const float*)d_in[3];
  const float* rope   = (const float*)d_in[4];
  char* ws = (char*)d_ws;
  u16* hid_b = (u16*)(ws + 0);
  u16* w_b   = (u16*)(ws + 16777216);
  u16* qb    = (u16*)(ws + 54525952);
  u16* kb    = (u16*)(ws + 71303168);
  u16* vtb   = (u16*)(ws + 72351744);
  u16* ctx   = hid_b;                      // reuse after GEMM1
  float* outf = (float*)d_out;

  k_cvt<<<2048, 256, 0, stream>>>(hs,   hid_b, SQL * HID / 8);
  k_cvt<<<2048, 256, 0, stream>>>(wqkv, w_b,   QKVD * HID / 8);
  k_gemm<0><<<dim3(QKVD / 128, SQL / 128), 256, 0, stream>>>(
      hid_b, w_b, bqkv, qb, kb, vtb, nullptr);
  k_rope<<<(SQL * 34 * 32) / 256, 256, 0, stream>>>(qb, kb, rope);
  k_cvt<<<2048, 256, 0, stream>>>(wdense, w_b, QDIM * HID / 8);   // after GEMM1
  k_attn<<<dim3(NHEADS, 8), 512, 0, stream>>>(qb, kb, vtb, ctx);
  k_gemm<1><<<dim3(QDIM / 128, SQL / 128), 256, 0, stream>>>(
      ctx, w_b, nullptr, nullptr, nullptr, nullptr, outf);
}